// Round 11
// baseline (218.313 us; speedup 1.0000x reference)
//
#include <hip/hip_runtime.h>
#include <hip/hip_bf16.h>
#include <math.h>

#define NB   4
#define CIN  128
#define HH   96
#define WW   96
#define HWN  (HH*WW)        // 9216
#define NHW  (NB*HWN)       // 36864
#define COUT 128
#define KW   9
#define KDIM (CIN*KW)       // 1152
#define GSZ  16
#define PXB  32             // pixels per dcn block
#define NBLK (NHW/PXB)      // 1152

typedef __attribute__((ext_vector_type(8))) short bf16x8;   // 8 bf16 (4 VGPRs)
typedef __attribute__((ext_vector_type(4))) float f32x4;    // 4 fp32 acc

// ws layout (float units)
#define OFF_WAH   0          // 73728 floats = 147456 ushorts: W hi, A-frag identity order
#define OFF_WAL   73728      // W lo
#define OFF_DX    147456
#define OFF_DY    184320
#define OFF_MASK  221184
#define OFF_GN    258048     // 128: s1[64], s2[64]
#define OFF_MAP   258240     // 256 ints: D-layout map[lane*4+reg] = (m<<4)|n
#define OFF_PAIR  258496     // 32 ints: B-slot j holds channel pairB[j]

__device__ __forceinline__ ushort f2bf(float f) {
    union { float f; uint u; } v; v.f = f;
    uint r = v.u + 0x7fffu + ((v.u >> 16) & 1u);   // RNE to bf16
    return (ushort)(r >> 16);
}
__device__ __forceinline__ float bf2f(ushort h) {
    union { uint u; float f; } v; v.u = ((uint)h) << 16;
    return v.f;
}

// Workgroup barrier that drains LDS ops but leaves global loads in flight:
// s_waitcnt lgkmcnt(0) + s_barrier, with a memory clobber so the compiler
// keeps LDS writes above / LDS reads below, without pinning the schedule.
__device__ __forceinline__ void barrier_keep_vm() {
    asm volatile("s_waitcnt lgkmcnt(0)\n\ts_barrier" ::: "memory");
}

// ------------------------------------------------- pre: head (b<576) + wsplit/probes (b>=576)
__global__ __launch_bounds__(256) void pre_kernel(const float* __restrict__ x,
                                                  const float* __restrict__ w_head,
                                                  const float* __restrict__ b_head,
                                                  const float* __restrict__ wd,
                                                  ushort* __restrict__ wah,
                                                  ushort* __restrict__ wal,
                                                  float* __restrict__ dxv,
                                                  float* __restrict__ dyv,
                                                  float* __restrict__ maskv,
                                                  float* __restrict__ gn_part,
                                                  int* __restrict__ map,
                                                  int* __restrict__ pairB) {
    __shared__ float wl[3456];          // head: wl[(c*9+kk)*3 + j]
    __shared__ float sp[4][64][3];
    const int b = blockIdx.x, t = threadIdx.x;

    if (b >= 576) {
        // ---------------- prep part (r8-proven)
        const int bb = b - 576;
        int i = bb * 256 + t;                     // < 147456
        {
            int e  = i & 7;
            int l  = (i >> 3) & 63;
            int ot = (i >> 9) & 7;
            int q  = (i >> 12) & 3;
            int k  = i >> 14;                     // 0..8
            int o  = ot * 16 + (l & 15);
            int c  = q * 32 + (l >> 4) * 8 + e;
            float w = wd[o * KDIM + c * KW + k];
            ushort h = f2bf(w);
            wah[i] = h;
            wal[i] = f2bf(w - bf2f(h));
        }
        if (bb == 0 && t < 128) gn_part[t] = 0.f;
        if (bb == 0 && t < 64) {
            // D-layout probe (HW-verified r4/r6)
            int l = t;
            bf16x8 A1 = {}, B1 = {}, A2 = {}, B2 = {};
            if ((l >> 4) == 0) {
                A1[0] = (short)f2bf((float)((l & 15) + 1));
                B1[0] = (short)f2bf(1.0f);
                A2[0] = (short)f2bf(1.0f);
                B2[0] = (short)f2bf((float)((l & 15) + 1));
            }
            f32x4 d1 = {0.f,0.f,0.f,0.f}, d2 = {0.f,0.f,0.f,0.f};
            d1 = __builtin_amdgcn_mfma_f32_16x16x32_bf16(A1, B1, d1, 0, 0, 0);
            d2 = __builtin_amdgcn_mfma_f32_16x16x32_bf16(A2, B2, d2, 0, 0, 0);
#pragma unroll
            for (int r = 0; r < 4; ++r) {
                int m = (int)(d1[r] + 0.5f) - 1;
                int n = (int)(d2[r] + 0.5f) - 1;
                map[l * 4 + r] = (m << 4) | n;
            }
        }
        if (bb == 1 && t < 64) {
            // A/B k-slot pairing probe (HW-verified r6): pairB[j] = s
            int l = t;
            union { bf16x8 v; short a[8]; } B;
#pragma unroll
            for (int e = 0; e < 8; ++e) {
                float val = (float)(1u << (((l >> 4) * 8 + e) & 31));
                B.a[e] = (short)f2bf(val);
            }
#pragma unroll
            for (int s = 0; s < 32; ++s) {
                union { bf16x8 v; short a[8]; } A;
#pragma unroll
                for (int e = 0; e < 8; ++e) A.a[e] = 0;
                if ((l >> 4) == (s >> 3)) A.a[s & 7] = (short)f2bf(1.0f);
                f32x4 d = {0.f, 0.f, 0.f, 0.f};
                d = __builtin_amdgcn_mfma_f32_16x16x32_bf16(A.v, B.v, d, 0, 0, 0);
                float v0 = d[0];
                if (l == 0 && v0 > 0.f) {
                    int ex; frexpf(v0, &ex);     // v0 = 2^j -> ex = j+1
                    int j = ex - 1;
                    if (j >= 0 && j < 32) pairB[j] = s;
                }
            }
        }
        return;
    }

    // ---------------- head part (r8-proven): 64 px x 4 c-groups, LDS reduce
    for (int i = t; i < 3456; i += 256) {
        int j = i / KDIM, r = i - j * KDIM;
        wl[r * 3 + j] = w_head[i];
    }
    __syncthreads();

    int lane = t & 63, cg = t >> 6;
    int p = b * 64 + lane;
    int n = p / HWN, hw = p % HWN;
    int h = hw / WW, w = hw % WW;

    int   offs[9];
    float msk[9];
#pragma unroll
    for (int ky = 0; ky < 3; ky++)
#pragma unroll
        for (int kx = 0; kx < 3; kx++) {
            int yy = h - 1 + ky, xx = w - 1 + kx;
            bool ok = (yy >= 0) && (yy < HH) && (xx >= 0) && (xx < WW);
            int yc = min(max(yy, 0), HH - 1), xc = min(max(xx, 0), WW - 1);
            offs[ky * 3 + kx] = yc * WW + xc;
            msk[ky * 3 + kx] = ok ? 1.f : 0.f;
        }

    float a0 = 0.f, a1 = 0.f, a2 = 0.f;
    const float* xn = x + (size_t)n * CIN * HWN;
    for (int c = cg * 32; c < cg * 32 + 32; c++) {
        const float* xc = xn + c * HWN;
        const float* wc = &wl[c * 27];
#pragma unroll
        for (int kk = 0; kk < 9; kk++) {
            float v = xc[offs[kk]] * msk[kk];
            a0 = fmaf(v, wc[kk * 3 + 0], a0);
            a1 = fmaf(v, wc[kk * 3 + 1], a1);
            a2 = fmaf(v, wc[kk * 3 + 2], a2);
        }
    }
    sp[cg][lane][0] = a0; sp[cg][lane][1] = a1; sp[cg][lane][2] = a2;
    __syncthreads();
    if (t < 64) {
        float b0 = sp[0][t][0] + sp[1][t][0] + sp[2][t][0] + sp[3][t][0] + b_head[0];
        float b1 = sp[0][t][1] + sp[1][t][1] + sp[2][t][1] + sp[3][t][1] + b_head[1];
        float b2 = sp[0][t][2] + sp[1][t][2] + sp[2][t][2] + sp[3][t][2] + b_head[2];
        int pp = b * 64 + t;
        dxv[pp]   = 0.25f * tanhf(b0);
        dyv[pp]   = 0.25f * tanhf(b1);
        maskv[pp] = 1.f / (1.f + expf(-b2));
    }
}

// ---------------------------------------------------------------- main DCN
// r8 dataflow + r9's software pipeline (PASSED in r9), with the perf bugs
// fixed: launch_bounds(256,4) -> 128-VGPR budget (no spill), asm lgkm-only
// barrier (prefetched gathers stay in flight), no sched_barrier pinning.
__global__ __launch_bounds__(256, 4) void dcn_kernel(const float* __restrict__ x,
                                                  const ushort* __restrict__ wah,
                                                  const ushort* __restrict__ wal,
                                                  const float* __restrict__ dxv,
                                                  const float* __restrict__ dyv,
                                                  const float* __restrict__ maskv,
                                                  const int* __restrict__ map,
                                                  const int* __restrict__ pairB,
                                                  float* __restrict__ out,
                                                  float* __restrict__ gn_part) {
    __shared__ __attribute__((aligned(16))) ushort sBh[2][4 * PXB * 8];  // 4 KB
    __shared__ __attribute__((aligned(16))) ushort sBl[2][4 * PXB * 8];  // 4 KB
    __shared__ float sMask[PXB];
    __shared__ float gred[16];

    const int t = threadIdx.x;
    const int lane = t & 63;
    const int wv = t >> 6;
    const int lg = lane >> 4;
    const int ml = lane & 15;
    const int pix = t & 31;
    const int sg  = t >> 5;         // 0..7: slot quad sg*4..sg*4+3

    int b = blockIdx.x;
    int nb = (b & 7) * (NBLK / 8) + (b >> 3);     // XCD swizzle
    const int p0  = nb * PXB;
    const int n   = p0 / HWN;
    const int hw0 = p0 % HWN;
    const float* xn = x + (size_t)n * CIN * HWN;

    if (t < PXB) sMask[t] = maskv[p0 + t];
    if (t < 16) gred[t] = 0.f;

    const float dxl = dxv[p0 + pix];
    const float dyl = dyv[p0 + pix];
    const int hme = (hw0 + pix) / WW;
    const int wme = (hw0 + pix) % WW;

    int chn[4];
#pragma unroll
    for (int e = 0; e < 4; ++e) chn[e] = pairB[sg * 4 + e] & 31;

    f32x4 acc[2][2];
#pragma unroll
    for (int i = 0; i < 2; i++)
#pragma unroll
        for (int j = 0; j < 2; j++) acc[i][j] = (f32x4){0.f, 0.f, 0.f, 0.f};

    const int oyc[9] = {0, 0, 0, 1, 0, -1, 1, 1, -1};
    const int oxc[9] = {0, 1, -1, 0, 0, 0, 1, -1, 1};
    const int ncl[9] = {1, 2, 2, 2, 1, 2, 4, 4, 4};

    int aa[4]; float wq[4];
    float raw[4][4];                 // [channel e][corner] — prefetched gathers
    bf16x8 An0, An1, An2, An3;       // prefetched A frags (hi0,hi1,lo0,lo1)

    // ---- prologue: corners tap0, issue chunk(0,0) gathers + A frags
    {
        float py = (float)(hme - 1), px = (float)(wme - 1);
        float fy0 = floorf(py), fx0 = floorf(px);
        int y0 = (int)fy0, x0 = (int)fx0;
        float fy = py - fy0, fx = px - fx0;
#pragma unroll
        for (int j = 0; j < 4; ++j) {
            int yy = y0 + (j >> 1), xx = x0 + (j & 1);
            float wb = ((j >> 1) ? fy : 1.f - fy) * ((j & 1) ? fx : 1.f - fx);
            bool ok = (yy >= 0) && (yy < HH) && (xx >= 0) && (xx < WW);
            aa[j] = min(max(yy, 0), HH - 1) * WW + min(max(xx, 0), WW - 1);
            wq[j] = ok ? wb : 0.f;
        }
#pragma unroll
        for (int e = 0; e < 4; ++e) raw[e][0] = xn[(size_t)chn[e] * HWN + aa[0]];
        const size_t abase = (size_t)(wv * 2) * 512 + lane * 8;
        An0 = *(const bf16x8*)(wah + abase);
        An1 = *(const bf16x8*)(wah + abase + 512);
        An2 = *(const bf16x8*)(wal + abase);
        An3 = *(const bf16x8*)(wal + abase + 512);
    }

#pragma unroll
    for (int j = 0; j < 36; ++j) {
        const int k = j >> 2;
        const int NC = ncl[k];
        // current A frags
        bf16x8 Ah0 = An0, Ah1 = An1, Al0 = An2, Al1 = An3;
        // ---- pack set j (waits on j's gathers — issued one iteration ago)
        union { short4 v; ushort u[4]; } hv, lv;
#pragma unroll
        for (int e = 0; e < 4; ++e) {
            float s = raw[e][0] * wq[0];
            if (NC >= 2) s += raw[e][1] * wq[1];
            if (NC == 4) s += raw[e][2] * wq[2] + raw[e][3] * wq[3];
            ushort hh = f2bf(s);
            hv.u[e] = hh;
            lv.u[e] = f2bf(s - bf2f(hh));
        }
        const int wbase = ((sg >> 1) * PXB + pix) * 8 + (sg & 1) * 4;
        *(short4*)&sBh[j & 1][wbase] = hv.v;
        *(short4*)&sBl[j & 1][wbase] = lv.v;
        // ---- prefetch set j+1 (global loads stay in flight across the barrier)
        if (j < 35) {
            const int jn = j + 1, kn = jn >> 2, qn = jn & 3;
            if (qn == 0) {
                const int ky = kn / 3, kx = kn - ky * 3;
                float py = (float)(hme - 1 + ky) + (float)oyc[kn] * dxl;
                float px = (float)(wme - 1 + kx) + (float)oxc[kn] * dyl;
                float fy0 = floorf(py), fx0 = floorf(px);
                int y0 = (int)fy0, x0 = (int)fx0;
                float fy = py - fy0, fx = px - fx0;
#pragma unroll
                for (int jj = 0; jj < 4; ++jj) {
                    int yy = y0 + (jj >> 1), xx = x0 + (jj & 1);
                    float wb = ((jj >> 1) ? fy : 1.f - fy) * ((jj & 1) ? fx : 1.f - fx);
                    bool ok = (yy >= 0) && (yy < HH) && (xx >= 0) && (xx < WW);
                    aa[jj] = min(max(yy, 0), HH - 1) * WW + min(max(xx, 0), WW - 1);
                    wq[jj] = ok ? wb : 0.f;
                }
                if (ncl[kn] == 2 && oxc[kn] == 0) { aa[1] = aa[2]; wq[1] = wq[2]; }
            }
            const int NCn = ncl[kn];
            const int ccn = qn * 32;
#pragma unroll
            for (int e = 0; e < 4; ++e) {
                const float* xc = xn + (size_t)(ccn + chn[e]) * HWN;
                raw[e][0] = xc[aa[0]];
                if (NCn >= 2) raw[e][1] = xc[aa[1]];
                if (NCn == 4) { raw[e][2] = xc[aa[2]]; raw[e][3] = xc[aa[3]]; }
            }
            const size_t abase = (size_t)((kn * 4 + qn) * 8 + wv * 2) * 512 + lane * 8;
            An0 = *(const bf16x8*)(wah + abase);
            An1 = *(const bf16x8*)(wah + abase + 512);
            An2 = *(const bf16x8*)(wal + abase);
            An3 = *(const bf16x8*)(wal + abase + 512);
        }
        barrier_keep_vm();   // drains LDS writes; gathers stay outstanding
        // ---- MFMAs on buf[j&1]
#pragma unroll
        for (int pt = 0; pt < 2; ++pt) {
            const int rbase = (lg * PXB + pt * 16 + ml) * 8;
            bf16x8 Bh = *(const bf16x8*)&sBh[j & 1][rbase];
            bf16x8 Bl = *(const bf16x8*)&sBl[j & 1][rbase];
            acc[0][pt] = __builtin_amdgcn_mfma_f32_16x16x32_bf16(Ah0, Bh, acc[0][pt], 0, 0, 0);
            acc[0][pt] = __builtin_amdgcn_mfma_f32_16x16x32_bf16(Ah0, Bl, acc[0][pt], 0, 0, 0);
            acc[0][pt] = __builtin_amdgcn_mfma_f32_16x16x32_bf16(Al0, Bh, acc[0][pt], 0, 0, 0);
            acc[1][pt] = __builtin_amdgcn_mfma_f32_16x16x32_bf16(Ah1, Bh, acc[1][pt], 0, 0, 0);
            acc[1][pt] = __builtin_amdgcn_mfma_f32_16x16x32_bf16(Ah1, Bl, acc[1][pt], 0, 0, 0);
            acc[1][pt] = __builtin_amdgcn_mfma_f32_16x16x32_bf16(Al1, Bh, acc[1][pt], 0, 0, 0);
        }
    }

    // ---- epilogue: mask, scatter via probed D layout, GN partials (r8-proven)
    int4 mn4 = *(const int4*)&map[lane * 4];
    int mn[4] = {mn4.x, mn4.y, mn4.z, mn4.w};
    float s1g[2] = {0.f, 0.f}, s2g[2] = {0.f, 0.f};
#pragma unroll
    for (int ot = 0; ot < 2; ++ot) {
        int otile = wv * 32 + ot * 16;
#pragma unroll
        for (int pt = 0; pt < 2; ++pt) {
#pragma unroll
            for (int r = 0; r < 4; ++r) {
                int m = mn[r] >> 4, nn2 = mn[r] & 15;
                int p = pt * 16 + nn2;
                float v = acc[ot][pt][r] * sMask[p];
                s1g[ot] += v;
                s2g[ot] += v * v;
                out[((size_t)n * COUT + otile + m) * HWN + hw0 + p] = v;
            }
        }
    }
#pragma unroll
    for (int ot = 0; ot < 2; ++ot) {
        int g = wv * 2 + ot;
        atomicAdd(&gred[g * 2 + 0], s1g[ot]);
        atomicAdd(&gred[g * 2 + 1], s2g[ot]);
    }
    __syncthreads();
    if (t < 8) {
        atomicAdd(&gn_part[n * 8 + t],      gred[t * 2 + 0]);
        atomicAdd(&gn_part[64 + n * 8 + t], gred[t * 2 + 1]);
    }
}

// ---------------------------------------------------------------- GN apply (stats inline)
__global__ __launch_bounds__(256) void gn_apply(float* __restrict__ out,
                                                const float* __restrict__ gn_part,
                                                const float* __restrict__ gamma,
                                                const float* __restrict__ beta) {
    int i4 = blockIdx.x * 256 + threadIdx.x;
    size_t e = (size_t)i4 * 4;
    int og = (int)(e / HWN);
    int n = og >> 7, o = og & 127;
    int s = n * 8 + (o >> 4);
    const float cnt = (float)GSZ * (float)HWN;
    float s1 = gn_part[s], s2 = gn_part[64 + s];
    float mu = s1 / cnt;
    float var = s2 / cnt - mu * mu;
    float inv = rsqrtf(var + 1e-5f);
    float ga = gamma[o] * inv;
    float be = beta[o] - mu * ga;
    float4 v = *(float4*)(out + e);
    v.x = fmaxf(fmaf(v.x, ga, be), 0.f);
    v.y = fmaxf(fmaf(v.y, ga, be), 0.f);
    v.z = fmaxf(fmaf(v.z, ga, be), 0.f);
    v.w = fmaxf(fmaf(v.w, ga, be), 0.f);
    *(float4*)(out + e) = v;
}

// ---------------------------------------------------------------- launch
extern "C" void kernel_launch(void* const* d_in, const int* in_sizes, int n_in,
                              void* d_out, int out_size, void* d_ws, size_t ws_size,
                              hipStream_t stream) {
    const float* x       = (const float*)d_in[0];
    const float* w_head  = (const float*)d_in[1];
    const float* b_head  = (const float*)d_in[2];
    const float* w_dcn   = (const float*)d_in[3];
    const float* gamma   = (const float*)d_in[4];
    const float* beta    = (const float*)d_in[5];
    float* out = (float*)d_out;
    float* ws  = (float*)d_ws;

    ushort* wah    = (ushort*)(ws + OFF_WAH);
    ushort* wal    = (ushort*)(ws + OFF_WAL);
    float* dxv     = ws + OFF_DX;
    float* dyv     = ws + OFF_DY;
    float* maskv   = ws + OFF_MASK;
    float* gn_part = ws + OFF_GN;
    int*   map     = (int*)(ws + OFF_MAP);
    int*   pairB   = (int*)(ws + OFF_PAIR);

    pre_kernel<<<1152, 256, 0, stream>>>(x, w_head, b_head, w_dcn, wah, wal,
                                         dxv, dyv, maskv, gn_part, map, pairB);
    dcn_kernel<<<NBLK, 256, 0, stream>>>(x, wah, wal, dxv, dyv, maskv, map, pairB, out, gn_part);
    gn_apply<<<(NB * COUT * HWN) / 4 / 256, 256, 0, stream>>>(out, gn_part, gamma, beta);
}

// Round 12
// 181.437 us; speedup vs baseline: 1.2032x; 1.2032x over previous
//
#include <hip/hip_runtime.h>
#include <hip/hip_bf16.h>
#include <math.h>

#define NB   4
#define CIN  128
#define HH   96
#define WW   96
#define HWN  (HH*WW)        // 9216
#define NHW  (NB*HWN)       // 36864
#define COUT 128
#define KW   9
#define KDIM (CIN*KW)       // 1152
#define GSZ  16
#define PXB  32             // pixels per dcn block
#define NBLK (NHW/PXB)      // 1152

typedef __attribute__((ext_vector_type(8))) short bf16x8;   // 8 bf16 (4 VGPRs)
typedef __attribute__((ext_vector_type(4))) float f32x4;    // 4 fp32 acc

// ws layout (float units)
#define OFF_WAH   0          // 73728 floats = 147456 ushorts: W hi, A-frag identity order
#define OFF_DX    147456
#define OFF_DY    184320
#define OFF_MASK  221184
#define OFF_GN    258048     // 128: s1[64], s2[64]
#define OFF_MAP   258240     // 256 ints: D-layout map[lane*4+reg] = (m<<4)|n
#define OFF_PAIR  258496     // 32 ints: B-slot j holds channel pairB[j]

__device__ __forceinline__ ushort f2bf(float f) {
    union { float f; uint u; } v; v.f = f;
    uint r = v.u + 0x7fffu + ((v.u >> 16) & 1u);   // RNE to bf16
    return (ushort)(r >> 16);
}
__device__ __forceinline__ float bf2f(ushort h) {
    union { uint u; float f; } v; v.u = ((uint)h) << 16;
    return v.f;
}

// Workgroup barrier that drains LDS ops but leaves global loads in flight
// (r9/r11-proven correct).
__device__ __forceinline__ void barrier_keep_vm() {
    asm volatile("s_waitcnt lgkmcnt(0)\n\ts_barrier" ::: "memory");
}

// ------------------------------------------------- pre: head (b<576) + wsplit/probes (b>=576)
__global__ __launch_bounds__(256) void pre_kernel(const float* __restrict__ x,
                                                  const float* __restrict__ w_head,
                                                  const float* __restrict__ b_head,
                                                  const float* __restrict__ wd,
                                                  ushort* __restrict__ wah,
                                                  float* __restrict__ dxv,
                                                  float* __restrict__ dyv,
                                                  float* __restrict__ maskv,
                                                  float* __restrict__ gn_part,
                                                  int* __restrict__ map,
                                                  int* __restrict__ pairB) {
    __shared__ float wl[3456];          // head: wl[(c*9+kk)*3 + j]
    __shared__ float sp[4][64][3];
    const int b = blockIdx.x, t = threadIdx.x;

    if (b >= 576) {
        // ---------------- prep part (r8-proven indexing), hi only
        const int bb = b - 576;
        int i = bb * 256 + t;                     // < 147456
        {
            int e  = i & 7;
            int l  = (i >> 3) & 63;
            int ot = (i >> 9) & 7;
            int q  = (i >> 12) & 3;
            int k  = i >> 14;                     // 0..8
            int o  = ot * 16 + (l & 15);
            int c  = q * 32 + (l >> 4) * 8 + e;
            wah[i] = f2bf(wd[o * KDIM + c * KW + k]);
        }
        if (bb == 0 && t < 128) gn_part[t] = 0.f;
        if (bb == 0 && t < 64) {
            // D-layout probe (HW-verified r4/r6)
            int l = t;
            bf16x8 A1 = {}, B1 = {}, A2 = {}, B2 = {};
            if ((l >> 4) == 0) {
                A1[0] = (short)f2bf((float)((l & 15) + 1));
                B1[0] = (short)f2bf(1.0f);
                A2[0] = (short)f2bf(1.0f);
                B2[0] = (short)f2bf((float)((l & 15) + 1));
            }
            f32x4 d1 = {0.f,0.f,0.f,0.f}, d2 = {0.f,0.f,0.f,0.f};
            d1 = __builtin_amdgcn_mfma_f32_16x16x32_bf16(A1, B1, d1, 0, 0, 0);
            d2 = __builtin_amdgcn_mfma_f32_16x16x32_bf16(A2, B2, d2, 0, 0, 0);
#pragma unroll
            for (int r = 0; r < 4; ++r) {
                int m = (int)(d1[r] + 0.5f) - 1;
                int n = (int)(d2[r] + 0.5f) - 1;
                map[l * 4 + r] = (m << 4) | n;
            }
        }
        if (bb == 1 && t < 64) {
            // A/B k-slot pairing probe (HW-verified r6): pairB[j] = s
            int l = t;
            union { bf16x8 v; short a[8]; } B;
#pragma unroll
            for (int e = 0; e < 8; ++e) {
                float val = (float)(1u << (((l >> 4) * 8 + e) & 31));
                B.a[e] = (short)f2bf(val);
            }
#pragma unroll
            for (int s = 0; s < 32; ++s) {
                union { bf16x8 v; short a[8]; } A;
#pragma unroll
                for (int e = 0; e < 8; ++e) A.a[e] = 0;
                if ((l >> 4) == (s >> 3)) A.a[s & 7] = (short)f2bf(1.0f);
                f32x4 d = {0.f, 0.f, 0.f, 0.f};
                d = __builtin_amdgcn_mfma_f32_16x16x32_bf16(A.v, B.v, d, 0, 0, 0);
                float v0 = d[0];
                if (l == 0 && v0 > 0.f) {
                    int ex; frexpf(v0, &ex);     // v0 = 2^j -> ex = j+1
                    int j = ex - 1;
                    if (j >= 0 && j < 32) pairB[j] = s;
                }
            }
        }
        return;
    }

    // ---------------- head part (r8-proven): 64 px x 4 c-groups, LDS reduce
    for (int i = t; i < 3456; i += 256) {
        int j = i / KDIM, r = i - j * KDIM;
        wl[r * 3 + j] = w_head[i];
    }
    __syncthreads();

    int lane = t & 63, cg = t >> 6;
    int p = b * 64 + lane;
    int n = p / HWN, hw = p % HWN;
    int h = hw / WW, w = hw % WW;

    int   offs[9];
    float msk[9];
#pragma unroll
    for (int ky = 0; ky < 3; ky++)
#pragma unroll
        for (int kx = 0; kx < 3; kx++) {
            int yy = h - 1 + ky, xx = w - 1 + kx;
            bool ok = (yy >= 0) && (yy < HH) && (xx >= 0) && (xx < WW);
            int yc = min(max(yy, 0), HH - 1), xc = min(max(xx, 0), WW - 1);
            offs[ky * 3 + kx] = yc * WW + xc;
            msk[ky * 3 + kx] = ok ? 1.f : 0.f;
        }

    float a0 = 0.f, a1 = 0.f, a2 = 0.f;
    const float* xn = x + (size_t)n * CIN * HWN;
    for (int c = cg * 32; c < cg * 32 + 32; c++) {
        const float* xc = xn + c * HWN;
        const float* wc = &wl[c * 27];
#pragma unroll
        for (int kk = 0; kk < 9; kk++) {
            float v = xc[offs[kk]] * msk[kk];
            a0 = fmaf(v, wc[kk * 3 + 0], a0);
            a1 = fmaf(v, wc[kk * 3 + 1], a1);
            a2 = fmaf(v, wc[kk * 3 + 2], a2);
        }
    }
    sp[cg][lane][0] = a0; sp[cg][lane][1] = a1; sp[cg][lane][2] = a2;
    __syncthreads();
    if (t < 64) {
        float b0 = sp[0][t][0] + sp[1][t][0] + sp[2][t][0] + sp[3][t][0] + b_head[0];
        float b1 = sp[0][t][1] + sp[1][t][1] + sp[2][t][1] + sp[3][t][1] + b_head[1];
        float b2 = sp[0][t][2] + sp[1][t][2] + sp[2][t][2] + sp[3][t][2] + b_head[2];
        int pp = b * 64 + t;
        dxv[pp]   = 0.25f * tanhf(b0);
        dyv[pp]   = 0.25f * tanhf(b1);
        maskv[pp] = 1.f / (1.f + expf(-b2));
    }
}

// ---------------------------------------------------------------- main DCN
// r11's pipeline skeleton (PASSED), plain-bf16 (no lo path): 4 MFMAs/chunk,
// half the LDS, ~48 live regs across the barrier -> fits 60-VGPR budget, no spill.
__global__ __launch_bounds__(256) void dcn_kernel(const float* __restrict__ x,
                                                  const ushort* __restrict__ wah,
                                                  const float* __restrict__ dxv,
                                                  const float* __restrict__ dyv,
                                                  const float* __restrict__ maskv,
                                                  const int* __restrict__ map,
                                                  const int* __restrict__ pairB,
                                                  float* __restrict__ out,
                                                  float* __restrict__ gn_part) {
    __shared__ __attribute__((aligned(16))) ushort sBh[2][4 * PXB * 8];  // 4 KB
    __shared__ float sMask[PXB];
    __shared__ float gred[16];

    const int t = threadIdx.x;
    const int lane = t & 63;
    const int wv = t >> 6;
    const int lg = lane >> 4;
    const int ml = lane & 15;
    const int pix = t & 31;
    const int sg  = t >> 5;         // 0..7: slot quad sg*4..sg*4+3

    int b = blockIdx.x;
    int nb = (b & 7) * (NBLK / 8) + (b >> 3);     // XCD swizzle
    const int p0  = nb * PXB;
    const int n   = p0 / HWN;
    const int hw0 = p0 % HWN;
    const float* xn = x + (size_t)n * CIN * HWN;

    if (t < PXB) sMask[t] = maskv[p0 + t];
    if (t < 16) gred[t] = 0.f;

    const float dxl = dxv[p0 + pix];
    const float dyl = dyv[p0 + pix];
    const int hme = (hw0 + pix) / WW;
    const int wme = (hw0 + pix) % WW;

    int chn[4];
#pragma unroll
    for (int e = 0; e < 4; ++e) chn[e] = pairB[sg * 4 + e] & 31;

    f32x4 acc[2][2];
#pragma unroll
    for (int i = 0; i < 2; i++)
#pragma unroll
        for (int j = 0; j < 2; j++) acc[i][j] = (f32x4){0.f, 0.f, 0.f, 0.f};

    const int oyc[9] = {0, 0, 0, 1, 0, -1, 1, 1, -1};
    const int oxc[9] = {0, 1, -1, 0, 0, 0, 1, -1, 1};
    const int ncl[9] = {1, 2, 2, 2, 1, 2, 4, 4, 4};

    int aa[4]; float wq[4];
    float raw[4][4];                 // [channel e][corner] — prefetched gathers
    bf16x8 An0, An1;                 // prefetched A frags (hi only)

    // ---- prologue: corners tap0, issue chunk(0,0) gathers + A frags
    {
        float py = (float)(hme - 1), px = (float)(wme - 1);
        float fy0 = floorf(py), fx0 = floorf(px);
        int y0 = (int)fy0, x0 = (int)fx0;
        float fy = py - fy0, fx = px - fx0;
#pragma unroll
        for (int j = 0; j < 4; ++j) {
            int yy = y0 + (j >> 1), xx = x0 + (j & 1);
            float wb = ((j >> 1) ? fy : 1.f - fy) * ((j & 1) ? fx : 1.f - fx);
            bool ok = (yy >= 0) && (yy < HH) && (xx >= 0) && (xx < WW);
            aa[j] = min(max(yy, 0), HH - 1) * WW + min(max(xx, 0), WW - 1);
            wq[j] = ok ? wb : 0.f;
        }
#pragma unroll
        for (int e = 0; e < 4; ++e) raw[e][0] = xn[(size_t)chn[e] * HWN + aa[0]];
        const size_t abase = (size_t)(wv * 2) * 512 + lane * 8;
        An0 = *(const bf16x8*)(wah + abase);
        An1 = *(const bf16x8*)(wah + abase + 512);
    }

#pragma unroll
    for (int j = 0; j < 36; ++j) {
        const int k = j >> 2;
        const int NC = ncl[k];
        // current A frags
        bf16x8 Ah0 = An0, Ah1 = An1;
        // ---- pack set j (waits on j's gathers — issued one iteration ago)
        union { short4 v; ushort u[4]; } hv;
#pragma unroll
        for (int e = 0; e < 4; ++e) {
            float s = raw[e][0] * wq[0];
            if (NC >= 2) s += raw[e][1] * wq[1];
            if (NC == 4) s += raw[e][2] * wq[2] + raw[e][3] * wq[3];
            hv.u[e] = f2bf(s);
        }
        const int wbase = ((sg >> 1) * PXB + pix) * 8 + (sg & 1) * 4;
        *(short4*)&sBh[j & 1][wbase] = hv.v;
        // ---- prefetch set j+1 (global loads stay in flight across the barrier)
        if (j < 35) {
            const int jn = j + 1, kn = jn >> 2, qn = jn & 3;
            if (qn == 0) {
                const int ky = kn / 3, kx = kn - ky * 3;
                float py = (float)(hme - 1 + ky) + (float)oyc[kn] * dxl;
                float px = (float)(wme - 1 + kx) + (float)oxc[kn] * dyl;
                float fy0 = floorf(py), fx0 = floorf(px);
                int y0 = (int)fy0, x0 = (int)fx0;
                float fy = py - fy0, fx = px - fx0;
#pragma unroll
                for (int jj = 0; jj < 4; ++jj) {
                    int yy = y0 + (jj >> 1), xx = x0 + (jj & 1);
                    float wb = ((jj >> 1) ? fy : 1.f - fy) * ((jj & 1) ? fx : 1.f - fx);
                    bool ok = (yy >= 0) && (yy < HH) && (xx >= 0) && (xx < WW);
                    aa[jj] = min(max(yy, 0), HH - 1) * WW + min(max(xx, 0), WW - 1);
                    wq[jj] = ok ? wb : 0.f;
                }
                if (ncl[kn] == 2 && oxc[kn] == 0) { aa[1] = aa[2]; wq[1] = wq[2]; }
            }
            const int NCn = ncl[kn];
            const int ccn = qn * 32;
#pragma unroll
            for (int e = 0; e < 4; ++e) {
                const float* xc = xn + (size_t)(ccn + chn[e]) * HWN;
                raw[e][0] = xc[aa[0]];
                if (NCn >= 2) raw[e][1] = xc[aa[1]];
                if (NCn == 4) { raw[e][2] = xc[aa[2]]; raw[e][3] = xc[aa[3]]; }
            }
            const size_t abase = (size_t)((kn * 4 + qn) * 8 + wv * 2) * 512 + lane * 8;
            An0 = *(const bf16x8*)(wah + abase);
            An1 = *(const bf16x8*)(wah + abase + 512);
        }
        barrier_keep_vm();   // drains LDS writes; gathers stay outstanding
        // ---- MFMAs on buf[j&1]
#pragma unroll
        for (int pt = 0; pt < 2; ++pt) {
            const int rbase = (lg * PXB + pt * 16 + ml) * 8;
            bf16x8 Bh = *(const bf16x8*)&sBh[j & 1][rbase];
            acc[0][pt] = __builtin_amdgcn_mfma_f32_16x16x32_bf16(Ah0, Bh, acc[0][pt], 0, 0, 0);
            acc[1][pt] = __builtin_amdgcn_mfma_f32_16x16x32_bf16(Ah1, Bh, acc[1][pt], 0, 0, 0);
        }
    }

    // ---- epilogue: mask, scatter via probed D layout, GN partials (r8-proven)
    int4 mn4 = *(const int4*)&map[lane * 4];
    int mn[4] = {mn4.x, mn4.y, mn4.z, mn4.w};
    float s1g[2] = {0.f, 0.f}, s2g[2] = {0.f, 0.f};
#pragma unroll
    for (int ot = 0; ot < 2; ++ot) {
        int otile = wv * 32 + ot * 16;
#pragma unroll
        for (int pt = 0; pt < 2; ++pt) {
#pragma unroll
            for (int r = 0; r < 4; ++r) {
                int m = mn[r] >> 4, nn2 = mn[r] & 15;
                int p = pt * 16 + nn2;
                float v = acc[ot][pt][r] * sMask[p];
                s1g[ot] += v;
                s2g[ot] += v * v;
                out[((size_t)n * COUT + otile + m) * HWN + hw0 + p] = v;
            }
        }
    }
#pragma unroll
    for (int ot = 0; ot < 2; ++ot) {
        int g = wv * 2 + ot;
        atomicAdd(&gred[g * 2 + 0], s1g[ot]);
        atomicAdd(&gred[g * 2 + 1], s2g[ot]);
    }
    __syncthreads();
    if (t < 8) {
        atomicAdd(&gn_part[n * 8 + t],      gred[t * 2 + 0]);
        atomicAdd(&gn_part[64 + n * 8 + t], gred[t * 2 + 1]);
    }
}

// ---------------------------------------------------------------- GN apply (stats inline)
__global__ __launch_bounds__(256) void gn_apply(float* __restrict__ out,
                                                const float* __restrict__ gn_part,
                                                const float* __restrict__ gamma,
                                                const float* __restrict__ beta) {
    int i4 = blockIdx.x * 256 + threadIdx.x;
    size_t e = (size_t)i4 * 4;
    int og = (int)(e / HWN);
    int n = og >> 7, o = og & 127;
    int s = n * 8 + (o >> 4);
    const float cnt = (float)GSZ * (float)HWN;
    float s1 = gn_part[s], s2 = gn_part[64 + s];
    float mu = s1 / cnt;
    float var = s2 / cnt - mu * mu;
    float inv = rsqrtf(var + 1e-5f);
    float ga = gamma[o] * inv;
    float be = beta[o] - mu * ga;
    float4 v = *(float4*)(out + e);
    v.x = fmaxf(fmaf(v.x, ga, be), 0.f);
    v.y = fmaxf(fmaf(v.y, ga, be), 0.f);
    v.z = fmaxf(fmaf(v.z, ga, be), 0.f);
    v.w = fmaxf(fmaf(v.w, ga, be), 0.f);
    *(float4*)(out + e) = v;
}

// ---------------------------------------------------------------- launch
extern "C" void kernel_launch(void* const* d_in, const int* in_sizes, int n_in,
                              void* d_out, int out_size, void* d_ws, size_t ws_size,
                              hipStream_t stream) {
    const float* x       = (const float*)d_in[0];
    const float* w_head  = (const float*)d_in[1];
    const float* b_head  = (const float*)d_in[2];
    const float* w_dcn   = (const float*)d_in[3];
    const float* gamma   = (const float*)d_in[4];
    const float* beta    = (const float*)d_in[5];
    float* out = (float*)d_out;
    float* ws  = (float*)d_ws;

    ushort* wah    = (ushort*)(ws + OFF_WAH);
    float* dxv     = ws + OFF_DX;
    float* dyv     = ws + OFF_DY;
    float* maskv   = ws + OFF_MASK;
    float* gn_part = ws + OFF_GN;
    int*   map     = (int*)(ws + OFF_MAP);
    int*   pairB   = (int*)(ws + OFF_PAIR);

    pre_kernel<<<1152, 256, 0, stream>>>(x, w_head, b_head, w_dcn, wah,
                                         dxv, dyv, maskv, gn_part, map, pairB);
    dcn_kernel<<<NBLK, 256, 0, stream>>>(x, wah, dxv, dyv, maskv, map, pairB, out, gn_part);
    gn_apply<<<(NB * COUT * HWN) / 4 / 256, 256, 0, stream>>>(out, gn_part, gamma, beta);
}